// Round 4
// baseline (1345.417 us; speedup 1.0000x reference)
//
#include <hip/hip_runtime.h>

typedef unsigned short u16;
typedef short s16x8 __attribute__((ext_vector_type(8)));
typedef float f32x4 __attribute__((ext_vector_type(4)));

#define SLOPE 0.01f
#define EPB 64

__device__ __forceinline__ float leaky(float x) { return x >= 0.f ? x : SLOPE * x; }

__device__ __forceinline__ u16 f2b(float f) {          // round-to-nearest-even
    union { float f; unsigned u; } v; v.f = f;
    unsigned r = v.u + 0x7FFFu + ((v.u >> 16) & 1u);
    return (u16)(r >> 16);
}
__device__ __forceinline__ float b2f(u16 b) {
    union { unsigned u; float f; } v; v.u = ((unsigned)b) << 16; return v.f;
}

// ---------------------------------------------------------------------------
// Pass 0: find active edges (ntype[src]==2), compact their ids, mark recv dst.
// ---------------------------------------------------------------------------
__global__ __launch_bounds__(256) void k_build_active(
    const int* __restrict__ src, const int* __restrict__ dst,
    const int* __restrict__ ntype, int* __restrict__ list,
    int* __restrict__ cnt, float* __restrict__ recvf, int E)
{
    int e = blockIdx.x * 256 + threadIdx.x;
    if (e < E) {
        if (ntype[src[e]] == 2) {
            int p = atomicAdd(cnt, 1);
            list[p] = e;
            recvf[dst[e]] = 1.0f;
        }
    }
}

// ---------------------------------------------------------------------------
// fp32 -> bf16 bulk convert (n multiple of 4)
// ---------------------------------------------------------------------------
__global__ __launch_bounds__(256) void k_f2b(const float* __restrict__ in,
                                             u16* __restrict__ out, int n4)
{
    int i = blockIdx.x * 256 + threadIdx.x;
    if (i < n4) {
        float4 v = ((const float4*)in)[i];
        ushort4 o;
        o.x = f2b(v.x); o.y = f2b(v.y); o.z = f2b(v.z); o.w = f2b(v.w);
        ((ushort4*)out)[i] = o;
    }
}

// ---------------------------------------------------------------------------
// W [K][128] fp32 row-major  ->  WT [128][K] bf16 (n-major)
// ---------------------------------------------------------------------------
__global__ __launch_bounds__(256) void k_wt(const float* __restrict__ W,
                                            u16* __restrict__ WT, int K)
{
    int idx = blockIdx.x * 256 + threadIdx.x;
    if (idx < K * 128) {
        int k = idx >> 7, n = idx & 127;
        WT[n * K + k] = f2b(W[idx]);
    }
}

// ---------------------------------------------------------------------------
// T = h @ [We_src | We_dst]  via bf16 MFMA, fp32 accumulate.
// A: [M][128] bf16.  WT: [2][128 n][128 k] bf16.  T out: [M][256] bf16.
// block 256 = 4 waves (2x2), tile 128x128, BK=64.
// ---------------------------------------------------------------------------
__global__ __launch_bounds__(256) void k_gemm_T(
    const u16* __restrict__ A, const u16* __restrict__ WT,
    u16* __restrict__ T, int M)
{
    __shared__ u16 As[128][72];
    __shared__ u16 Bs[128][72];
    const int t = threadIdx.x;
    const int m0 = blockIdx.x * 128;
    const int sel = blockIdx.y;
    const u16* Wp = WT + (size_t)sel * 128 * 128;
    const int w = t >> 6, lane = t & 63, wm = w >> 1, wn = w & 1;
    f32x4 acc[4][4] = {};

    const int row = t >> 1, koff = (t & 1) * 32;
    const int gm_s = m0 + row;

    for (int kt = 0; kt < 128; kt += 64) {
        #pragma unroll
        for (int j = 0; j < 4; ++j) {
            int4 va = make_int4(0, 0, 0, 0);
            if (gm_s < M) va = *(const int4*)(A + (size_t)gm_s * 128 + kt + koff + j * 8);
            *(int4*)&As[row][koff + j * 8] = va;
            *(int4*)&Bs[row][koff + j * 8] =
                *(const int4*)(Wp + (size_t)row * 128 + kt + koff + j * 8);
        }
        __syncthreads();
        #pragma unroll
        for (int kf = 0; kf < 2; ++kf) {
            s16x8 a[4], b[4];
            #pragma unroll
            for (int mi = 0; mi < 4; ++mi)
                a[mi] = *(const s16x8*)&As[wm * 64 + mi * 16 + (lane & 15)][kf * 32 + (lane >> 4) * 8];
            #pragma unroll
            for (int ni = 0; ni < 4; ++ni)
                b[ni] = *(const s16x8*)&Bs[wn * 64 + ni * 16 + (lane & 15)][kf * 32 + (lane >> 4) * 8];
            #pragma unroll
            for (int mi = 0; mi < 4; ++mi)
                #pragma unroll
                for (int ni = 0; ni < 4; ++ni)
                    acc[mi][ni] = __builtin_amdgcn_mfma_f32_16x16x32_bf16(
                        a[mi], b[ni], acc[mi][ni], 0, 0, 0);
        }
        __syncthreads();
    }
    const int lr = (lane >> 4) * 4, lc = lane & 15;
    const int ncol0 = sel * 128 + wn * 64;
    #pragma unroll
    for (int mi = 0; mi < 4; ++mi) {
        #pragma unroll
        for (int r = 0; r < 4; ++r) {
            int gm = m0 + wm * 64 + mi * 16 + lr + r;
            if (gm < M) {
                #pragma unroll
                for (int ni = 0; ni < 4; ++ni)
                    T[(size_t)gm * 256 + ncol0 + ni * 16 + lc] = f2b(acc[mi][ni][r]);
            }
        }
    }
}

// ---------------------------------------------------------------------------
// out = leaky([H | R] @ Wn) * recv.  H bf16 [M][128], R fp32 [M][128],
// WT [128 n][256 k] bf16.  fin=1 -> write fp32 to O32, else bf16 to O16.
// ---------------------------------------------------------------------------
__global__ __launch_bounds__(256) void k_gemm_node(
    const u16* __restrict__ H, const float* __restrict__ R,
    const u16* __restrict__ WT, const float* __restrict__ recvf,
    u16* __restrict__ O16, float* __restrict__ O32, int fin, int M)
{
    __shared__ u16 As[128][72];
    __shared__ u16 Bs[128][72];
    const int t = threadIdx.x;
    const int m0 = blockIdx.x * 128;
    const int w = t >> 6, lane = t & 63, wm = w >> 1, wn = w & 1;
    f32x4 acc[4][4] = {};

    const int row = t >> 1, koff = (t & 1) * 32;
    const int gm_s = m0 + row;

    for (int kt = 0; kt < 256; kt += 64) {
        if (kt < 128) {
            #pragma unroll
            for (int j = 0; j < 4; ++j) {
                int4 va = make_int4(0, 0, 0, 0);
                if (gm_s < M) va = *(const int4*)(H + (size_t)gm_s * 128 + kt + koff + j * 8);
                *(int4*)&As[row][koff + j * 8] = va;
            }
        } else {
            #pragma unroll
            for (int j = 0; j < 8; ++j) {
                float4 v = make_float4(0.f, 0.f, 0.f, 0.f);
                if (gm_s < M) v = *(const float4*)(R + (size_t)gm_s * 128 + (kt - 128) + koff + j * 4);
                ushort4 o;
                o.x = f2b(v.x); o.y = f2b(v.y); o.z = f2b(v.z); o.w = f2b(v.w);
                *(ushort4*)&As[row][koff + j * 4] = o;
            }
        }
        #pragma unroll
        for (int j = 0; j < 4; ++j)
            *(int4*)&Bs[row][koff + j * 8] =
                *(const int4*)(WT + (size_t)row * 256 + kt + koff + j * 8);
        __syncthreads();
        #pragma unroll
        for (int kf = 0; kf < 2; ++kf) {
            s16x8 a[4], b[4];
            #pragma unroll
            for (int mi = 0; mi < 4; ++mi)
                a[mi] = *(const s16x8*)&As[wm * 64 + mi * 16 + (lane & 15)][kf * 32 + (lane >> 4) * 8];
            #pragma unroll
            for (int ni = 0; ni < 4; ++ni)
                b[ni] = *(const s16x8*)&Bs[wn * 64 + ni * 16 + (lane & 15)][kf * 32 + (lane >> 4) * 8];
            #pragma unroll
            for (int mi = 0; mi < 4; ++mi)
                #pragma unroll
                for (int ni = 0; ni < 4; ++ni)
                    acc[mi][ni] = __builtin_amdgcn_mfma_f32_16x16x32_bf16(
                        a[mi], b[ni], acc[mi][ni], 0, 0, 0);
        }
        __syncthreads();
    }
    const int lr = (lane >> 4) * 4, lc = lane & 15;
    #pragma unroll
    for (int mi = 0; mi < 4; ++mi) {
        #pragma unroll
        for (int r = 0; r < 4; ++r) {
            int gm = m0 + wm * 64 + mi * 16 + lr + r;
            if (gm < M) {
                float rv = recvf[gm];
                #pragma unroll
                for (int ni = 0; ni < 4; ++ni) {
                    float val = leaky(acc[mi][ni][r]) * rv;
                    size_t o = (size_t)gm * 128 + wn * 64 + ni * 16 + lc;
                    if (fin) O32[o] = val;
                    else     O16[o] = f2b(val);
                }
            }
        }
    }
}

// ---------------------------------------------------------------------------
// Edge pass, MFMA matvec. 64 edges/block (16 per wave).
// msg^T[128 n][64 e] = We_ef^T[128][64] (x) ef_tile[64 e][64 k]  (bf16 MFMA)
// Lane owns ONE edge (col = lane&15), 32 n-features (rows).
//   val = leaky(msg + T[s][n] + T[d][128+n]);  atomicAdd(red[d][n], val)
// ---------------------------------------------------------------------------
__global__ __launch_bounds__(256) void k_edge(
    const float* __restrict__ ef, const u16* __restrict__ WTef,  // [128 n][64 k] bf16
    const u16* __restrict__ T16, const int* __restrict__ list,
    const int* __restrict__ cntp, const int* __restrict__ src,
    const int* __restrict__ dst, float* __restrict__ red)
{
    __shared__ u16 Et[64][72];          // edge-major ef tile (bf16, padded)
    __shared__ int es[EPB], ss[EPB], dd[EPB];

    const int t = threadIdx.x;
    const int cnt = *cntp;
    const int b0 = blockIdx.x * EPB;
    if (b0 >= cnt) return;

    if (t < EPB) {
        int pos = b0 + t;
        int e = (pos < cnt) ? list[pos] : -1;
        es[t] = e;
        ss[t] = (e >= 0) ? src[e] : 0;
        dd[t] = (e >= 0) ? dst[e] : 0;
    }
    __syncthreads();

    #pragma unroll
    for (int p = 0; p < 4; ++p) {       // stage ef: 64 edges x 16 float4
        int idx = t + p * 256;
        int edge = idx >> 4, f4 = idx & 15;
        int e = es[edge];
        float4 v = make_float4(0.f, 0.f, 0.f, 0.f);
        if (e >= 0) v = *(const float4*)(ef + (size_t)e * 64 + f4 * 4);
        ushort4 o;
        o.x = f2b(v.x); o.y = f2b(v.y); o.z = f2b(v.z); o.w = f2b(v.w);
        *(ushort4*)&Et[edge][f4 * 4] = o;
    }
    __syncthreads();

    const int w = t >> 6, lane = t & 63;
    const int lo = lane & 15, q = lane >> 4;

    f32x4 acc[8] = {};
    #pragma unroll
    for (int kf = 0; kf < 2; ++kf) {
        s16x8 b = *(const s16x8*)&Et[w * 16 + lo][kf * 32 + q * 8];
        #pragma unroll
        for (int mi = 0; mi < 8; ++mi) {
            s16x8 a = *(const s16x8*)(WTef + (size_t)(mi * 16 + lo) * 64 + kf * 32 + q * 8);
            acc[mi] = __builtin_amdgcn_mfma_f32_16x16x32_bf16(a, b, acc[mi], 0, 0, 0);
        }
    }

    const int ei = w * 16 + lo;
    if (b0 + ei < cnt) {
        const int s = ss[ei], d = dd[ei];
        const u16* Ts = T16 + (size_t)s * 256;
        const u16* Td = T16 + (size_t)d * 256 + 128;
        float* rd = red + (size_t)d * 128;
        #pragma unroll
        for (int mi = 0; mi < 8; ++mi) {
            int n0 = mi * 16 + q * 4;
            ushort4 ts = *(const ushort4*)(Ts + n0);
            ushort4 td = *(const ushort4*)(Td + n0);
            atomicAdd(rd + n0 + 0, leaky(acc[mi][0] + b2f(ts.x) + b2f(td.x)));
            atomicAdd(rd + n0 + 1, leaky(acc[mi][1] + b2f(ts.y) + b2f(td.y)));
            atomicAdd(rd + n0 + 2, leaky(acc[mi][2] + b2f(ts.z) + b2f(td.z)));
            atomicAdd(rd + n0 + 3, leaky(acc[mi][3] + b2f(ts.w) + b2f(td.w)));
        }
    }
}

// ---------------------------------------------------------------------------
extern "C" void kernel_launch(void* const* d_in, const int* in_sizes, int n_in,
                              void* d_out, int out_size, void* d_ws, size_t ws_size,
                              hipStream_t stream)
{
    const float* nf    = (const float*)d_in[0];
    const float* ef    = (const float*)d_in[1];
    const int*   src   = (const int*)d_in[2];
    const int*   dst   = (const int*)d_in[3];
    const int*   ntype = (const int*)d_in[4];
    const float* We[3] = {(const float*)d_in[5], (const float*)d_in[7], (const float*)d_in[9]};
    const float* Wn[3] = {(const float*)d_in[6], (const float*)d_in[8], (const float*)d_in[10]};

    const int N = in_sizes[0] / 128;
    const int E = in_sizes[1] / 64;

    u16* T16  = (u16*)d_ws;                        // N*256
    u16* hb0  = T16 + (size_t)N * 256;             // N*128
    u16* hb1  = hb0 + (size_t)N * 128;             // N*128
    u16* WTe  = hb1 + (size_t)N * 128;             // 3 * 2 * 128*128
    u16* WTn  = WTe + 3 * 2 * 128 * 128;           // 3 * 128*256
    u16* WTef = WTn + 3 * 128 * 256;               // 3 * 128*64
    float* red   = (float*)(WTef + 3 * 128 * 64);  // N*128 fp32
    float* recvf = red + (size_t)N * 128;          // N
    int*   list  = (int*)(recvf + N);              // E
    int*   cnt   = list + E;                       // 1

    hipMemsetAsync(cnt, 0, sizeof(int), stream);
    hipMemsetAsync(recvf, 0, (size_t)N * sizeof(float), stream);
    k_build_active<<<(E + 255) / 256, 256, 0, stream>>>(src, dst, ntype, list, cnt, recvf, E);

    // nf -> bf16
    k_f2b<<<(N * 128 / 4 + 255) / 256, 256, 0, stream>>>(nf, hb0, N * 128 / 4);

    // per-layer weight transposes (bf16)
    for (int l = 0; l < 3; ++l) {
        k_wt<<<(128 * 128 + 255) / 256, 256, 0, stream>>>(We[l],             WTe + (size_t)l * 2 * 16384,         128);
        k_wt<<<(128 * 128 + 255) / 256, 256, 0, stream>>>(We[l] + 128 * 128, WTe + (size_t)l * 2 * 16384 + 16384, 128);
        k_wt<<<(256 * 128 + 255) / 256, 256, 0, stream>>>(Wn[l],             WTn + (size_t)l * 32768,             256);
        k_wt<<<(64 * 128 + 255) / 256, 256, 0, stream>>>(We[l] + 256 * 128,  WTef + (size_t)l * 8192,             64);
    }

    dim3 gT((N + 127) / 128, 2);
    dim3 gN((N + 127) / 128, 1);
    int  gE = (E + EPB - 1) / EPB;

    const u16* hIn[3]  = {hb0, hb1, hb0};
    u16*       hOut[3] = {hb1, hb0, hb1};
    for (int l = 0; l < 3; ++l) {
        int fin = (l == 2);
        k_gemm_T<<<gT, 256, 0, stream>>>(hIn[l], WTe + (size_t)l * 2 * 16384, T16, N);
        hipMemsetAsync(red, 0, (size_t)N * 128 * sizeof(float), stream);
        k_edge<<<gE, 256, 0, stream>>>(ef, WTef + (size_t)l * 8192, T16, list, cnt, src, dst, red);
        k_gemm_node<<<gN, 256, 0, stream>>>(hIn[l], red, WTn + (size_t)l * 32768,
                                            recvf, hOut[l], (float*)d_out, fin, N);
    }
}

// Round 5
// 642.097 us; speedup vs baseline: 2.0953x; 2.0953x over previous
//
#include <hip/hip_runtime.h>

typedef unsigned short u16;
typedef short s16x8 __attribute__((ext_vector_type(8)));
typedef float f32x4 __attribute__((ext_vector_type(4)));

#define SLOPE 0.01f
#define EPB 64

__device__ __forceinline__ float leaky(float x) { return x >= 0.f ? x : SLOPE * x; }

__device__ __forceinline__ u16 f2b(float f) {          // round-to-nearest-even
    union { float f; unsigned u; } v; v.f = f;
    unsigned r = v.u + 0x7FFFu + ((v.u >> 16) & 1u);
    return (u16)(r >> 16);
}
__device__ __forceinline__ float b2f(u16 b) {
    union { unsigned u; float f; } v; v.u = ((unsigned)b) << 16; return v.f;
}

// ---------------------------------------------------------------------------
// Pass 0: find active edges (ntype[src]==2), compact their ids, mark recv dst.
// ---------------------------------------------------------------------------
__global__ __launch_bounds__(256) void k_build_active(
    const int* __restrict__ src, const int* __restrict__ dst,
    const int* __restrict__ ntype, int* __restrict__ list,
    int* __restrict__ cnt, float* __restrict__ recvf, int E)
{
    int e = blockIdx.x * 256 + threadIdx.x;
    if (e < E) {
        if (ntype[src[e]] == 2) {
            int p = atomicAdd(cnt, 1);
            list[p] = e;
            recvf[dst[e]] = 1.0f;
        }
    }
}

// ---------------------------------------------------------------------------
// fp32 -> bf16 bulk convert (n multiple of 4)
// ---------------------------------------------------------------------------
__global__ __launch_bounds__(256) void k_f2b(const float* __restrict__ in,
                                             u16* __restrict__ out, int n4)
{
    int i = blockIdx.x * 256 + threadIdx.x;
    if (i < n4) {
        float4 v = ((const float4*)in)[i];
        ushort4 o;
        o.x = f2b(v.x); o.y = f2b(v.y); o.z = f2b(v.z); o.w = f2b(v.w);
        ((ushort4*)out)[i] = o;
    }
}

// ---------------------------------------------------------------------------
// W [K][128] fp32 row-major  ->  WT [128][K] bf16 (n-major)
// ---------------------------------------------------------------------------
__global__ __launch_bounds__(256) void k_wt(const float* __restrict__ W,
                                            u16* __restrict__ WT, int K)
{
    int idx = blockIdx.x * 256 + threadIdx.x;
    if (idx < K * 128) {
        int k = idx >> 7, n = idx & 127;
        WT[n * K + k] = f2b(W[idx]);
    }
}

// ---------------------------------------------------------------------------
// T = h @ [We_src | We_dst]  via bf16 MFMA, fp32 accumulate.
// A: [M][128] bf16.  WT: [2][128 n][128 k] bf16.  T out: [M][256] bf16.
// block 256 = 4 waves (2x2), tile 128x128, BK=64.
// ---------------------------------------------------------------------------
__global__ __launch_bounds__(256) void k_gemm_T(
    const u16* __restrict__ A, const u16* __restrict__ WT,
    u16* __restrict__ T, int M)
{
    __shared__ u16 As[128][72];
    __shared__ u16 Bs[128][72];
    const int t = threadIdx.x;
    const int m0 = blockIdx.x * 128;
    const int sel = blockIdx.y;
    const u16* Wp = WT + (size_t)sel * 128 * 128;
    const int w = t >> 6, lane = t & 63, wm = w >> 1, wn = w & 1;
    f32x4 acc[4][4] = {};

    const int row = t >> 1, koff = (t & 1) * 32;
    const int gm_s = m0 + row;

    for (int kt = 0; kt < 128; kt += 64) {
        #pragma unroll
        for (int j = 0; j < 4; ++j) {
            int4 va = make_int4(0, 0, 0, 0);
            if (gm_s < M) va = *(const int4*)(A + (size_t)gm_s * 128 + kt + koff + j * 8);
            *(int4*)&As[row][koff + j * 8] = va;
            *(int4*)&Bs[row][koff + j * 8] =
                *(const int4*)(Wp + (size_t)row * 128 + kt + koff + j * 8);
        }
        __syncthreads();
        #pragma unroll
        for (int kf = 0; kf < 2; ++kf) {
            s16x8 a[4], b[4];
            #pragma unroll
            for (int mi = 0; mi < 4; ++mi)
                a[mi] = *(const s16x8*)&As[wm * 64 + mi * 16 + (lane & 15)][kf * 32 + (lane >> 4) * 8];
            #pragma unroll
            for (int ni = 0; ni < 4; ++ni)
                b[ni] = *(const s16x8*)&Bs[wn * 64 + ni * 16 + (lane & 15)][kf * 32 + (lane >> 4) * 8];
            #pragma unroll
            for (int mi = 0; mi < 4; ++mi)
                #pragma unroll
                for (int ni = 0; ni < 4; ++ni)
                    acc[mi][ni] = __builtin_amdgcn_mfma_f32_16x16x32_bf16(
                        a[mi], b[ni], acc[mi][ni], 0, 0, 0);
        }
        __syncthreads();
    }
    const int lr = (lane >> 4) * 4, lc = lane & 15;
    const int ncol0 = sel * 128 + wn * 64;
    #pragma unroll
    for (int mi = 0; mi < 4; ++mi) {
        #pragma unroll
        for (int r = 0; r < 4; ++r) {
            int gm = m0 + wm * 64 + mi * 16 + lr + r;
            if (gm < M) {
                #pragma unroll
                for (int ni = 0; ni < 4; ++ni)
                    T[(size_t)gm * 256 + ncol0 + ni * 16 + lc] = f2b(acc[mi][ni][r]);
            }
        }
    }
}

// ---------------------------------------------------------------------------
// out = leaky([H | R] @ Wn) * recv.  H bf16 [M][128], R fp32 [M][128],
// WT [128 n][256 k] bf16.  fin=1 -> write fp32 to O32, else bf16 to O16.
// ---------------------------------------------------------------------------
__global__ __launch_bounds__(256) void k_gemm_node(
    const u16* __restrict__ H, const float* __restrict__ R,
    const u16* __restrict__ WT, const float* __restrict__ recvf,
    u16* __restrict__ O16, float* __restrict__ O32, int fin, int M)
{
    __shared__ u16 As[128][72];
    __shared__ u16 Bs[128][72];
    const int t = threadIdx.x;
    const int m0 = blockIdx.x * 128;
    const int w = t >> 6, lane = t & 63, wm = w >> 1, wn = w & 1;
    f32x4 acc[4][4] = {};

    const int row = t >> 1, koff = (t & 1) * 32;
    const int gm_s = m0 + row;

    for (int kt = 0; kt < 256; kt += 64) {
        if (kt < 128) {
            #pragma unroll
            for (int j = 0; j < 4; ++j) {
                int4 va = make_int4(0, 0, 0, 0);
                if (gm_s < M) va = *(const int4*)(H + (size_t)gm_s * 128 + kt + koff + j * 8);
                *(int4*)&As[row][koff + j * 8] = va;
            }
        } else {
            #pragma unroll
            for (int j = 0; j < 8; ++j) {
                float4 v = make_float4(0.f, 0.f, 0.f, 0.f);
                if (gm_s < M) v = *(const float4*)(R + (size_t)gm_s * 128 + (kt - 128) + koff + j * 4);
                ushort4 o;
                o.x = f2b(v.x); o.y = f2b(v.y); o.z = f2b(v.z); o.w = f2b(v.w);
                *(ushort4*)&As[row][koff + j * 4] = o;
            }
        }
        #pragma unroll
        for (int j = 0; j < 4; ++j)
            *(int4*)&Bs[row][koff + j * 8] =
                *(const int4*)(WT + (size_t)row * 256 + kt + koff + j * 8);
        __syncthreads();
        #pragma unroll
        for (int kf = 0; kf < 2; ++kf) {
            s16x8 a[4], b[4];
            #pragma unroll
            for (int mi = 0; mi < 4; ++mi)
                a[mi] = *(const s16x8*)&As[wm * 64 + mi * 16 + (lane & 15)][kf * 32 + (lane >> 4) * 8];
            #pragma unroll
            for (int ni = 0; ni < 4; ++ni)
                b[ni] = *(const s16x8*)&Bs[wn * 64 + ni * 16 + (lane & 15)][kf * 32 + (lane >> 4) * 8];
            #pragma unroll
            for (int mi = 0; mi < 4; ++mi)
                #pragma unroll
                for (int ni = 0; ni < 4; ++ni)
                    acc[mi][ni] = __builtin_amdgcn_mfma_f32_16x16x32_bf16(
                        a[mi], b[ni], acc[mi][ni], 0, 0, 0);
        }
        __syncthreads();
    }
    const int lr = (lane >> 4) * 4, lc = lane & 15;
    #pragma unroll
    for (int mi = 0; mi < 4; ++mi) {
        #pragma unroll
        for (int r = 0; r < 4; ++r) {
            int gm = m0 + wm * 64 + mi * 16 + lr + r;
            if (gm < M) {
                float rv = recvf[gm];
                #pragma unroll
                for (int ni = 0; ni < 4; ++ni) {
                    float val = leaky(acc[mi][ni][r]) * rv;
                    size_t o = (size_t)gm * 128 + wn * 64 + ni * 16 + lc;
                    if (fin) O32[o] = val;
                    else     O16[o] = f2b(val);
                }
            }
        }
    }
}

// ---------------------------------------------------------------------------
// Edge pass v3: MFMA matvec + LDS transpose + COALESCED atomic scatter.
// Phase 1: stage ef tile (64 edges x 64 k, bf16).
// Phase 2: msg^T[128 n][64 e] = We_ef^T (x) ef  via MFMA; dump to Ms fp32.
// Phase 3 (round-3 style): wave w iterates its 16 edges; 64 lanes cover
//   contiguous n; 2 contiguous 256B wave-atomics per edge.
// ---------------------------------------------------------------------------
__global__ __launch_bounds__(256) void k_edge(
    const float* __restrict__ ef, const u16* __restrict__ WTef,  // [128 n][64 k] bf16
    const u16* __restrict__ T16, const int* __restrict__ list,
    const int* __restrict__ cntp, const int* __restrict__ src,
    const int* __restrict__ dst, float* __restrict__ red)
{
    __shared__ u16 Et[64][72];           // ef tile, edge-major bf16
    __shared__ float Ms[64][132];        // msg fp32, edge-major, padded
    __shared__ int es[EPB], ss[EPB], dd[EPB];

    const int t = threadIdx.x;
    const int cnt = *cntp;
    const int b0 = blockIdx.x * EPB;
    if (b0 >= cnt) return;

    if (t < EPB) {
        int pos = b0 + t;
        int e = (pos < cnt) ? list[pos] : -1;
        es[t] = e;
        ss[t] = (e >= 0) ? src[e] : 0;
        dd[t] = (e >= 0) ? dst[e] : 0;
    }
    __syncthreads();

    #pragma unroll
    for (int p = 0; p < 4; ++p) {        // stage ef: 64 edges x 16 float4
        int idx = t + p * 256;
        int edge = idx >> 4, f4 = idx & 15;
        int e = es[edge];
        float4 v = make_float4(0.f, 0.f, 0.f, 0.f);
        if (e >= 0) v = *(const float4*)(ef + (size_t)e * 64 + f4 * 4);
        ushort4 o;
        o.x = f2b(v.x); o.y = f2b(v.y); o.z = f2b(v.z); o.w = f2b(v.w);
        *(ushort4*)&Et[edge][f4 * 4] = o;
    }
    __syncthreads();

    const int w = t >> 6, lane = t & 63;
    const int lo = lane & 15, q = lane >> 4;
    const int ei = w * 16 + lo;          // this lane's edge slot

    f32x4 acc[8] = {};
    #pragma unroll
    for (int kf = 0; kf < 2; ++kf) {
        s16x8 b = *(const s16x8*)&Et[ei][kf * 32 + q * 8];
        #pragma unroll
        for (int mi = 0; mi < 8; ++mi) {
            s16x8 a = *(const s16x8*)(WTef + (size_t)(mi * 16 + lo) * 64 + kf * 32 + q * 8);
            acc[mi] = __builtin_amdgcn_mfma_f32_16x16x32_bf16(a, b, acc[mi], 0, 0, 0);
        }
    }
    // D mapping: col=lane&15 (edge), row = mi*16 + q*4 + r (feature n)
    #pragma unroll
    for (int mi = 0; mi < 8; ++mi)
        *(f32x4*)&Ms[ei][mi * 16 + q * 4] = acc[mi];
    __syncthreads();

    // scatter: wave w handles edges w*16 .. w*16+15 with coalesced atomics
    for (int ii = 0; ii < 16; ++ii) {
        int e2 = w * 16 + ii;
        if (b0 + e2 >= cnt) break;
        int s = ss[e2], d = dd[e2];
        float m0 = Ms[e2][lane], m1 = Ms[e2][64 + lane];
        float t0 = b2f(T16[(size_t)s * 256 + lane])      + b2f(T16[(size_t)d * 256 + 128 + lane]);
        float t1 = b2f(T16[(size_t)s * 256 + 64 + lane]) + b2f(T16[(size_t)d * 256 + 192 + lane]);
        atomicAdd(red + (size_t)d * 128 + lane,      leaky(m0 + t0));
        atomicAdd(red + (size_t)d * 128 + 64 + lane, leaky(m1 + t1));
    }
}

// ---------------------------------------------------------------------------
extern "C" void kernel_launch(void* const* d_in, const int* in_sizes, int n_in,
                              void* d_out, int out_size, void* d_ws, size_t ws_size,
                              hipStream_t stream)
{
    const float* nf    = (const float*)d_in[0];
    const float* ef    = (const float*)d_in[1];
    const int*   src   = (const int*)d_in[2];
    const int*   dst   = (const int*)d_in[3];
    const int*   ntype = (const int*)d_in[4];
    const float* We[3] = {(const float*)d_in[5], (const float*)d_in[7], (const float*)d_in[9]};
    const float* Wn[3] = {(const float*)d_in[6], (const float*)d_in[8], (const float*)d_in[10]};

    const int N = in_sizes[0] / 128;
    const int E = in_sizes[1] / 64;

    u16* T16  = (u16*)d_ws;                        // N*256
    u16* hb0  = T16 + (size_t)N * 256;             // N*128
    u16* hb1  = hb0 + (size_t)N * 128;             // N*128
    u16* WTe  = hb1 + (size_t)N * 128;             // 3 * 2 * 128*128
    u16* WTn  = WTe + 3 * 2 * 128 * 128;           // 3 * 128*256
    u16* WTef = WTn + 3 * 128 * 256;               // 3 * 128*64
    float* red   = (float*)(WTef + 3 * 128 * 64);  // N*128 fp32
    float* recvf = red + (size_t)N * 128;          // N
    int*   list  = (int*)(recvf + N);              // E
    int*   cnt   = list + E;                       // 1

    hipMemsetAsync(cnt, 0, sizeof(int), stream);
    hipMemsetAsync(recvf, 0, (size_t)N * sizeof(float), stream);
    k_build_active<<<(E + 255) / 256, 256, 0, stream>>>(src, dst, ntype, list, cnt, recvf, E);

    // nf -> bf16
    k_f2b<<<(N * 128 / 4 + 255) / 256, 256, 0, stream>>>(nf, hb0, N * 128 / 4);

    // per-layer weight transposes (bf16)
    for (int l = 0; l < 3; ++l) {
        k_wt<<<(128 * 128 + 255) / 256, 256, 0, stream>>>(We[l],             WTe + (size_t)l * 2 * 16384,         128);
        k_wt<<<(128 * 128 + 255) / 256, 256, 0, stream>>>(We[l] + 128 * 128, WTe + (size_t)l * 2 * 16384 + 16384, 128);
        k_wt<<<(256 * 128 + 255) / 256, 256, 0, stream>>>(Wn[l],             WTn + (size_t)l * 32768,             256);
        k_wt<<<(64 * 128 + 255) / 256, 256, 0, stream>>>(We[l] + 256 * 128,  WTef + (size_t)l * 8192,             64);
    }

    dim3 gT((N + 127) / 128, 2);
    dim3 gN((N + 127) / 128, 1);
    int  gE = (E + EPB - 1) / EPB;

    const u16* hIn[3]  = {hb0, hb1, hb0};
    u16*       hOut[3] = {hb1, hb0, hb1};
    for (int l = 0; l < 3; ++l) {
        int fin = (l == 2);
        k_gemm_T<<<gT, 256, 0, stream>>>(hIn[l], WTe + (size_t)l * 2 * 16384, T16, N);
        hipMemsetAsync(red, 0, (size_t)N * 128 * sizeof(float), stream);
        k_edge<<<gE, 256, 0, stream>>>(ef, WTef + (size_t)l * 8192, T16, list, cnt, src, dst, red);
        k_gemm_node<<<gN, 256, 0, stream>>>(hIn[l], red, WTn + (size_t)l * 32768,
                                            recvf, hOut[l], (float*)d_out, fin, N);
    }
}

// Round 6
// 536.058 us; speedup vs baseline: 2.5098x; 1.1978x over previous
//
#include <hip/hip_runtime.h>

typedef unsigned short u16;
typedef short s16x8 __attribute__((ext_vector_type(8)));
typedef float f32x4 __attribute__((ext_vector_type(4)));

#define SLOPE 0.01f
#define EPB 64

__device__ __forceinline__ float leaky(float x) { return x >= 0.f ? x : SLOPE * x; }

__device__ __forceinline__ u16 f2b(float f) {          // round-to-nearest-even
    union { float f; unsigned u; } v; v.f = f;
    unsigned r = v.u + 0x7FFFu + ((v.u >> 16) & 1u);
    return (u16)(r >> 16);
}
__device__ __forceinline__ float b2f(u16 b) {
    union { unsigned u; float f; } v; v.u = ((unsigned)b) << 16; return v.f;
}

// ---------------------------------------------------------------------------
// Pass 0: compact active edges (ntype[src]==2), mark recv dst.
// Block-aggregated compaction: ONE returning atomic per block (not per edge).
// ---------------------------------------------------------------------------
__global__ __launch_bounds__(256) void k_build_active(
    const int* __restrict__ src, const int* __restrict__ dst,
    const int* __restrict__ ntype, int* __restrict__ list,
    int* __restrict__ cnt, float* __restrict__ recvf, int E)
{
    __shared__ int wcnt[4];
    __shared__ int base;
    const int e = blockIdx.x * 256 + threadIdx.x;
    const int lane = threadIdx.x & 63, wv = threadIdx.x >> 6;

    bool pred = false;
    int d = 0;
    if (e < E) {
        d = dst[e];
        pred = (ntype[src[e]] == 2);
    }
    unsigned long long mask = __ballot(pred);
    if (lane == 0) wcnt[wv] = __popcll(mask);
    __syncthreads();
    if (threadIdx.x == 0)
        base = atomicAdd(cnt, wcnt[0] + wcnt[1] + wcnt[2] + wcnt[3]);
    __syncthreads();
    if (pred) {
        int off = base;
        #pragma unroll
        for (int i = 0; i < 3; ++i) if (i < wv) off += wcnt[i];
        off += __popcll(mask & ((1ull << lane) - 1ull));
        list[off] = e;
        recvf[d] = 1.0f;
    }
}

// ---------------------------------------------------------------------------
// fp32 -> bf16 bulk convert (n multiple of 4)
// ---------------------------------------------------------------------------
__global__ __launch_bounds__(256) void k_f2b(const float* __restrict__ in,
                                             u16* __restrict__ out, int n4)
{
    int i = blockIdx.x * 256 + threadIdx.x;
    if (i < n4) {
        float4 v = ((const float4*)in)[i];
        ushort4 o;
        o.x = f2b(v.x); o.y = f2b(v.y); o.z = f2b(v.z); o.w = f2b(v.w);
        ((ushort4*)out)[i] = o;
    }
}

// ---------------------------------------------------------------------------
// W [K][128] fp32 row-major  ->  WT [128][K] bf16 (n-major)
// ---------------------------------------------------------------------------
__global__ __launch_bounds__(256) void k_wt(const float* __restrict__ W,
                                            u16* __restrict__ WT, int K)
{
    int idx = blockIdx.x * 256 + threadIdx.x;
    if (idx < K * 128) {
        int k = idx >> 7, n = idx & 127;
        WT[n * K + k] = f2b(W[idx]);
    }
}

// ---------------------------------------------------------------------------
// T = h @ [We_src | We_dst]  via bf16 MFMA, fp32 accumulate.
// A: [M][128] bf16.  WT: [2][128 n][128 k] bf16.  T out: [M][256] bf16.
// block 256 = 4 waves (2x2), tile 128x128, BK=64.
// ---------------------------------------------------------------------------
__global__ __launch_bounds__(256) void k_gemm_T(
    const u16* __restrict__ A, const u16* __restrict__ WT,
    u16* __restrict__ T, int M)
{
    __shared__ u16 As[128][72];
    __shared__ u16 Bs[128][72];
    const int t = threadIdx.x;
    const int m0 = blockIdx.x * 128;
    const int sel = blockIdx.y;
    const u16* Wp = WT + (size_t)sel * 128 * 128;
    const int w = t >> 6, lane = t & 63, wm = w >> 1, wn = w & 1;
    f32x4 acc[4][4] = {};

    const int row = t >> 1, koff = (t & 1) * 32;
    const int gm_s = m0 + row;

    for (int kt = 0; kt < 128; kt += 64) {
        #pragma unroll
        for (int j = 0; j < 4; ++j) {
            int4 va = make_int4(0, 0, 0, 0);
            if (gm_s < M) va = *(const int4*)(A + (size_t)gm_s * 128 + kt + koff + j * 8);
            *(int4*)&As[row][koff + j * 8] = va;
            *(int4*)&Bs[row][koff + j * 8] =
                *(const int4*)(Wp + (size_t)row * 128 + kt + koff + j * 8);
        }
        __syncthreads();
        #pragma unroll
        for (int kf = 0; kf < 2; ++kf) {
            s16x8 a[4], b[4];
            #pragma unroll
            for (int mi = 0; mi < 4; ++mi)
                a[mi] = *(const s16x8*)&As[wm * 64 + mi * 16 + (lane & 15)][kf * 32 + (lane >> 4) * 8];
            #pragma unroll
            for (int ni = 0; ni < 4; ++ni)
                b[ni] = *(const s16x8*)&Bs[wn * 64 + ni * 16 + (lane & 15)][kf * 32 + (lane >> 4) * 8];
            #pragma unroll
            for (int mi = 0; mi < 4; ++mi)
                #pragma unroll
                for (int ni = 0; ni < 4; ++ni)
                    acc[mi][ni] = __builtin_amdgcn_mfma_f32_16x16x32_bf16(
                        a[mi], b[ni], acc[mi][ni], 0, 0, 0);
        }
        __syncthreads();
    }
    const int lr = (lane >> 4) * 4, lc = lane & 15;
    const int ncol0 = sel * 128 + wn * 64;
    #pragma unroll
    for (int mi = 0; mi < 4; ++mi) {
        #pragma unroll
        for (int r = 0; r < 4; ++r) {
            int gm = m0 + wm * 64 + mi * 16 + lr + r;
            if (gm < M) {
                #pragma unroll
                for (int ni = 0; ni < 4; ++ni)
                    T[(size_t)gm * 256 + ncol0 + ni * 16 + lc] = f2b(acc[mi][ni][r]);
            }
        }
    }
}

// ---------------------------------------------------------------------------
// out = leaky([H | R] @ Wn) * recv.  H bf16 [M][128], R fp32 [M][128],
// WT [128 n][256 k] bf16.  fin=1 -> write fp32 to O32, else bf16 to O16.
// ---------------------------------------------------------------------------
__global__ __launch_bounds__(256) void k_gemm_node(
    const u16* __restrict__ H, const float* __restrict__ R,
    const u16* __restrict__ WT, const float* __restrict__ recvf,
    u16* __restrict__ O16, float* __restrict__ O32, int fin, int M)
{
    __shared__ u16 As[128][72];
    __shared__ u16 Bs[128][72];
    const int t = threadIdx.x;
    const int m0 = blockIdx.x * 128;
    const int w = t >> 6, lane = t & 63, wm = w >> 1, wn = w & 1;
    f32x4 acc[4][4] = {};

    const int row = t >> 1, koff = (t & 1) * 32;
    const int gm_s = m0 + row;

    for (int kt = 0; kt < 256; kt += 64) {
        if (kt < 128) {
            #pragma unroll
            for (int j = 0; j < 4; ++j) {
                int4 va = make_int4(0, 0, 0, 0);
                if (gm_s < M) va = *(const int4*)(H + (size_t)gm_s * 128 + kt + koff + j * 8);
                *(int4*)&As[row][koff + j * 8] = va;
            }
        } else {
            #pragma unroll
            for (int j = 0; j < 8; ++j) {
                float4 v = make_float4(0.f, 0.f, 0.f, 0.f);
                if (gm_s < M) v = *(const float4*)(R + (size_t)gm_s * 128 + (kt - 128) + koff + j * 4);
                ushort4 o;
                o.x = f2b(v.x); o.y = f2b(v.y); o.z = f2b(v.z); o.w = f2b(v.w);
                *(ushort4*)&As[row][koff + j * 4] = o;
            }
        }
        #pragma unroll
        for (int j = 0; j < 4; ++j)
            *(int4*)&Bs[row][koff + j * 8] =
                *(const int4*)(WT + (size_t)row * 256 + kt + koff + j * 8);
        __syncthreads();
        #pragma unroll
        for (int kf = 0; kf < 2; ++kf) {
            s16x8 a[4], b[4];
            #pragma unroll
            for (int mi = 0; mi < 4; ++mi)
                a[mi] = *(const s16x8*)&As[wm * 64 + mi * 16 + (lane & 15)][kf * 32 + (lane >> 4) * 8];
            #pragma unroll
            for (int ni = 0; ni < 4; ++ni)
                b[ni] = *(const s16x8*)&Bs[wn * 64 + ni * 16 + (lane & 15)][kf * 32 + (lane >> 4) * 8];
            #pragma unroll
            for (int mi = 0; mi < 4; ++mi)
                #pragma unroll
                for (int ni = 0; ni < 4; ++ni)
                    acc[mi][ni] = __builtin_amdgcn_mfma_f32_16x16x32_bf16(
                        a[mi], b[ni], acc[mi][ni], 0, 0, 0);
        }
        __syncthreads();
    }
    const int lr = (lane >> 4) * 4, lc = lane & 15;
    #pragma unroll
    for (int mi = 0; mi < 4; ++mi) {
        #pragma unroll
        for (int r = 0; r < 4; ++r) {
            int gm = m0 + wm * 64 + mi * 16 + lr + r;
            if (gm < M) {
                float rv = recvf[gm];
                #pragma unroll
                for (int ni = 0; ni < 4; ++ni) {
                    float val = leaky(acc[mi][ni][r]) * rv;
                    size_t o = (size_t)gm * 128 + wn * 64 + ni * 16 + lc;
                    if (fin) O32[o] = val;
                    else     O16[o] = f2b(val);
                }
            }
        }
    }
}

// ---------------------------------------------------------------------------
// Edge pass: MFMA matvec + LDS transpose + coalesced atomic scatter.
// ---------------------------------------------------------------------------
__global__ __launch_bounds__(256) void k_edge(
    const float* __restrict__ ef, const u16* __restrict__ WTef,  // [128 n][64 k] bf16
    const u16* __restrict__ T16, const int* __restrict__ list,
    const int* __restrict__ cntp, const int* __restrict__ src,
    const int* __restrict__ dst, float* __restrict__ red)
{
    __shared__ u16 Et[64][72];           // ef tile, edge-major bf16
    __shared__ float Ms[64][132];        // msg fp32, edge-major, padded
    __shared__ int es[EPB], ss[EPB], dd[EPB];

    const int t = threadIdx.x;
    const int cnt = *cntp;
    const int b0 = blockIdx.x * EPB;
    if (b0 >= cnt) return;

    if (t < EPB) {
        int pos = b0 + t;
        int e = (pos < cnt) ? list[pos] : -1;
        es[t] = e;
        ss[t] = (e >= 0) ? src[e] : 0;
        dd[t] = (e >= 0) ? dst[e] : 0;
    }
    __syncthreads();

    #pragma unroll
    for (int p = 0; p < 4; ++p) {        // stage ef: 64 edges x 16 float4
        int idx = t + p * 256;
        int edge = idx >> 4, f4 = idx & 15;
        int e = es[edge];
        float4 v = make_float4(0.f, 0.f, 0.f, 0.f);
        if (e >= 0) v = *(const float4*)(ef + (size_t)e * 64 + f4 * 4);
        ushort4 o;
        o.x = f2b(v.x); o.y = f2b(v.y); o.z = f2b(v.z); o.w = f2b(v.w);
        *(ushort4*)&Et[edge][f4 * 4] = o;
    }
    __syncthreads();

    const int w = t >> 6, lane = t & 63;
    const int lo = lane & 15, q = lane >> 4;
    const int ei = w * 16 + lo;          // this lane's edge slot

    f32x4 acc[8] = {};
    #pragma unroll
    for (int kf = 0; kf < 2; ++kf) {
        s16x8 b = *(const s16x8*)&Et[ei][kf * 32 + q * 8];
        #pragma unroll
        for (int mi = 0; mi < 8; ++mi) {
            s16x8 a = *(const s16x8*)(WTef + (size_t)(mi * 16 + lo) * 64 + kf * 32 + q * 8);
            acc[mi] = __builtin_amdgcn_mfma_f32_16x16x32_bf16(a, b, acc[mi], 0, 0, 0);
        }
    }
    // D mapping: col=lane&15 (edge), row = mi*16 + q*4 + r (feature n)
    #pragma unroll
    for (int mi = 0; mi < 8; ++mi)
        *(f32x4*)&Ms[ei][mi * 16 + q * 4] = acc[mi];
    __syncthreads();

    // scatter: wave w handles edges w*16 .. w*16+15 with coalesced atomics
    for (int ii = 0; ii < 16; ++ii) {
        int e2 = w * 16 + ii;
        if (b0 + e2 >= cnt) break;
        int s = ss[e2], d = dd[e2];
        float m0 = Ms[e2][lane], m1 = Ms[e2][64 + lane];
        float t0 = b2f(T16[(size_t)s * 256 + lane])      + b2f(T16[(size_t)d * 256 + 128 + lane]);
        float t1 = b2f(T16[(size_t)s * 256 + 64 + lane]) + b2f(T16[(size_t)d * 256 + 192 + lane]);
        atomicAdd(red + (size_t)d * 128 + lane,      leaky(m0 + t0));
        atomicAdd(red + (size_t)d * 128 + 64 + lane, leaky(m1 + t1));
    }
}

// ---------------------------------------------------------------------------
extern "C" void kernel_launch(void* const* d_in, const int* in_sizes, int n_in,
                              void* d_out, int out_size, void* d_ws, size_t ws_size,
                              hipStream_t stream)
{
    const float* nf    = (const float*)d_in[0];
    const float* ef    = (const float*)d_in[1];
    const int*   src   = (const int*)d_in[2];
    const int*   dst   = (const int*)d_in[3];
    const int*   ntype = (const int*)d_in[4];
    const float* We[3] = {(const float*)d_in[5], (const float*)d_in[7], (const float*)d_in[9]};
    const float* Wn[3] = {(const float*)d_in[6], (const float*)d_in[8], (const float*)d_in[10]};

    const int N = in_sizes[0] / 128;
    const int E = in_sizes[1] / 64;

    u16* T16  = (u16*)d_ws;                        // N*256
    u16* hb0  = T16 + (size_t)N * 256;             // N*128
    u16* hb1  = hb0 + (size_t)N * 128;             // N*128
    u16* WTe  = hb1 + (size_t)N * 128;             // 3 * 2 * 128*128
    u16* WTn  = WTe + 3 * 2 * 128 * 128;           // 3 * 128*256
    u16* WTef = WTn + 3 * 128 * 256;               // 3 * 128*64
    float* red   = (float*)(WTef + 3 * 128 * 64);  // N*128 fp32
    float* recvf = red + (size_t)N * 128;          // N
    int*   list  = (int*)(recvf + N);              // E
    int*   cnt   = list + E;                       // 1

    hipMemsetAsync(cnt, 0, sizeof(int), stream);
    hipMemsetAsync(recvf, 0, (size_t)N * sizeof(float), stream);
    k_build_active<<<(E + 255) / 256, 256, 0, stream>>>(src, dst, ntype, list, cnt, recvf, E);

    // nf -> bf16
    k_f2b<<<(N * 128 / 4 + 255) / 256, 256, 0, stream>>>(nf, hb0, N * 128 / 4);

    // per-layer weight transposes (bf16)
    for (int l = 0; l < 3; ++l) {
        k_wt<<<(128 * 128 + 255) / 256, 256, 0, stream>>>(We[l],             WTe + (size_t)l * 2 * 16384,         128);
        k_wt<<<(128 * 128 + 255) / 256, 256, 0, stream>>>(We[l] + 128 * 128, WTe + (size_t)l * 2 * 16384 + 16384, 128);
        k_wt<<<(256 * 128 + 255) / 256, 256, 0, stream>>>(Wn[l],             WTn + (size_t)l * 32768,             256);
        k_wt<<<(64 * 128 + 255) / 256, 256, 0, stream>>>(We[l] + 256 * 128,  WTef + (size_t)l * 8192,             64);
    }

    dim3 gT((N + 127) / 128, 2);
    dim3 gN((N + 127) / 128, 1);
    int  gE = (E + EPB - 1) / EPB;

    const u16* hIn[3]  = {hb0, hb1, hb0};
    u16*       hOut[3] = {hb1, hb0, hb1};
    for (int l = 0; l < 3; ++l) {
        int fin = (l == 2);
        k_gemm_T<<<gT, 256, 0, stream>>>(hIn[l], WTe + (size_t)l * 2 * 16384, T16, N);
        hipMemsetAsync(red, 0, (size_t)N * 128 * sizeof(float), stream);
        k_edge<<<gE, 256, 0, stream>>>(ef, WTef + (size_t)l * 8192, T16, list, cnt, src, dst, red);
        k_gemm_node<<<gN, 256, 0, stream>>>(hIn[l], red, WTn + (size_t)l * 32768,
                                            recvf, hOut[l], (float*)d_out, fin, N);
    }
}

// Round 7
// 401.126 us; speedup vs baseline: 3.3541x; 1.3364x over previous
//
#include <hip/hip_runtime.h>

typedef unsigned short u16;
typedef short s16x8 __attribute__((ext_vector_type(8)));
typedef float f32x4 __attribute__((ext_vector_type(4)));

#define SLOPE 0.01f
#define EPB 64

__device__ __forceinline__ float leaky(float x) { return x >= 0.f ? x : SLOPE * x; }

__device__ __forceinline__ u16 f2b(float f) {          // round-to-nearest-even
    union { float f; unsigned u; } v; v.f = f;
    unsigned r = v.u + 0x7FFFu + ((v.u >> 16) & 1u);
    return (u16)(r >> 16);
}
__device__ __forceinline__ float b2f(u16 b) {
    union { unsigned u; float f; } v; v.u = ((unsigned)b) << 16; return v.f;
}

// ---------------------------------------------------------------------------
// Pass A: histogram active-edge dst counts + mark recv nodes.
// ---------------------------------------------------------------------------
__global__ __launch_bounds__(256) void k_hist(
    const int* __restrict__ src, const int* __restrict__ dst,
    const int* __restrict__ ntype, int* __restrict__ deg,
    float* __restrict__ recvf, int E)
{
    int e = blockIdx.x * 256 + threadIdx.x;
    if (e < E) {
        if (ntype[src[e]] == 2) {
            int d = dst[e];
            atomicAdd(&deg[d], 1);
            recvf[d] = 1.0f;
        }
    }
}

// ---------------------------------------------------------------------------
// Scan step 1: per-block (256-chunk) sums of deg.
// ---------------------------------------------------------------------------
__global__ __launch_bounds__(256) void k_scan1(
    const int* __restrict__ deg, int* __restrict__ bsum, int n)
{
    __shared__ int s[256];
    int i = blockIdx.x * 256 + threadIdx.x;
    s[threadIdx.x] = (i < n) ? deg[i] : 0;
    __syncthreads();
    for (int o = 128; o > 0; o >>= 1) {
        if (threadIdx.x < o) s[threadIdx.x] += s[threadIdx.x + o];
        __syncthreads();
    }
    if (threadIdx.x == 0) bsum[blockIdx.x] = s[0];
}

// ---------------------------------------------------------------------------
// Scan step 2: exclusive scan of block sums (nb <= 256) + total -> cnt.
// ---------------------------------------------------------------------------
__global__ __launch_bounds__(256) void k_scan2(
    int* __restrict__ bsum, int nb, int* __restrict__ cntp)
{
    __shared__ int s[256];
    int v = (threadIdx.x < nb) ? bsum[threadIdx.x] : 0;
    s[threadIdx.x] = v;
    __syncthreads();
    for (int o = 1; o < 256; o <<= 1) {
        int x = (threadIdx.x >= o) ? s[threadIdx.x - o] : 0;
        __syncthreads();
        s[threadIdx.x] += x;
        __syncthreads();
    }
    if (threadIdx.x < nb) bsum[threadIdx.x] = s[threadIdx.x] - v;  // exclusive
    if (threadIdx.x == 255) *cntp = s[255];                        // total
}

// ---------------------------------------------------------------------------
// Scan step 3: per-element exclusive offsets -> cursor (mutable copy).
// ---------------------------------------------------------------------------
__global__ __launch_bounds__(256) void k_scan3(
    const int* __restrict__ deg, const int* __restrict__ bexcl,
    int* __restrict__ cursor, int n)
{
    __shared__ int s[256];
    int i = blockIdx.x * 256 + threadIdx.x;
    int v = (i < n) ? deg[i] : 0;
    s[threadIdx.x] = v;
    __syncthreads();
    for (int o = 1; o < 256; o <<= 1) {
        int x = (threadIdx.x >= o) ? s[threadIdx.x - o] : 0;
        __syncthreads();
        s[threadIdx.x] += x;
        __syncthreads();
    }
    if (i < n) cursor[i] = bexcl[blockIdx.x] + s[threadIdx.x] - v;
}

// ---------------------------------------------------------------------------
// Pass B: scatter active edges into dst-sorted order via per-dst cursors.
// Contention per cursor ~avg degree (~4) -> cheap, unlike one global counter.
// ---------------------------------------------------------------------------
__global__ __launch_bounds__(256) void k_scatter_pos(
    const int* __restrict__ src, const int* __restrict__ dst,
    const int* __restrict__ ntype, int* __restrict__ cursor,
    int* __restrict__ eS, int* __restrict__ sSg, int* __restrict__ dSg, int E)
{
    int e = blockIdx.x * 256 + threadIdx.x;
    if (e < E) {
        int s = src[e];
        if (ntype[s] == 2) {
            int d = dst[e];
            int p = atomicAdd(&cursor[d], 1);
            eS[p] = e; sSg[p] = s; dSg[p] = d;
        }
    }
}

// ---------------------------------------------------------------------------
// fp32 -> bf16 bulk convert (n multiple of 4)
// ---------------------------------------------------------------------------
__global__ __launch_bounds__(256) void k_f2b(const float* __restrict__ in,
                                             u16* __restrict__ out, int n4)
{
    int i = blockIdx.x * 256 + threadIdx.x;
    if (i < n4) {
        float4 v = ((const float4*)in)[i];
        ushort4 o;
        o.x = f2b(v.x); o.y = f2b(v.y); o.z = f2b(v.z); o.w = f2b(v.w);
        ((ushort4*)out)[i] = o;
    }
}

// ---------------------------------------------------------------------------
// W [K][128] fp32 row-major  ->  WT [128][K] bf16 (n-major)
// ---------------------------------------------------------------------------
__global__ __launch_bounds__(256) void k_wt(const float* __restrict__ W,
                                            u16* __restrict__ WT, int K)
{
    int idx = blockIdx.x * 256 + threadIdx.x;
    if (idx < K * 128) {
        int k = idx >> 7, n = idx & 127;
        WT[n * K + k] = f2b(W[idx]);
    }
}

// ---------------------------------------------------------------------------
// T = h @ [We_src | We_dst]  via bf16 MFMA, fp32 accumulate.
// ---------------------------------------------------------------------------
__global__ __launch_bounds__(256) void k_gemm_T(
    const u16* __restrict__ A, const u16* __restrict__ WT,
    u16* __restrict__ T, int M)
{
    __shared__ u16 As[128][72];
    __shared__ u16 Bs[128][72];
    const int t = threadIdx.x;
    const int m0 = blockIdx.x * 128;
    const int sel = blockIdx.y;
    const u16* Wp = WT + (size_t)sel * 128 * 128;
    const int w = t >> 6, lane = t & 63, wm = w >> 1, wn = w & 1;
    f32x4 acc[4][4] = {};

    const int row = t >> 1, koff = (t & 1) * 32;
    const int gm_s = m0 + row;

    for (int kt = 0; kt < 128; kt += 64) {
        #pragma unroll
        for (int j = 0; j < 4; ++j) {
            int4 va = make_int4(0, 0, 0, 0);
            if (gm_s < M) va = *(const int4*)(A + (size_t)gm_s * 128 + kt + koff + j * 8);
            *(int4*)&As[row][koff + j * 8] = va;
            *(int4*)&Bs[row][koff + j * 8] =
                *(const int4*)(Wp + (size_t)row * 128 + kt + koff + j * 8);
        }
        __syncthreads();
        #pragma unroll
        for (int kf = 0; kf < 2; ++kf) {
            s16x8 a[4], b[4];
            #pragma unroll
            for (int mi = 0; mi < 4; ++mi)
                a[mi] = *(const s16x8*)&As[wm * 64 + mi * 16 + (lane & 15)][kf * 32 + (lane >> 4) * 8];
            #pragma unroll
            for (int ni = 0; ni < 4; ++ni)
                b[ni] = *(const s16x8*)&Bs[wn * 64 + ni * 16 + (lane & 15)][kf * 32 + (lane >> 4) * 8];
            #pragma unroll
            for (int mi = 0; mi < 4; ++mi)
                #pragma unroll
                for (int ni = 0; ni < 4; ++ni)
                    acc[mi][ni] = __builtin_amdgcn_mfma_f32_16x16x32_bf16(
                        a[mi], b[ni], acc[mi][ni], 0, 0, 0);
        }
        __syncthreads();
    }
    const int lr = (lane >> 4) * 4, lc = lane & 15;
    const int ncol0 = sel * 128 + wn * 64;
    #pragma unroll
    for (int mi = 0; mi < 4; ++mi) {
        #pragma unroll
        for (int r = 0; r < 4; ++r) {
            int gm = m0 + wm * 64 + mi * 16 + lr + r;
            if (gm < M) {
                #pragma unroll
                for (int ni = 0; ni < 4; ++ni)
                    T[(size_t)gm * 256 + ncol0 + ni * 16 + lc] = f2b(acc[mi][ni][r]);
            }
        }
    }
}

// ---------------------------------------------------------------------------
// out = leaky([H | R] @ Wn) * recv.
// ---------------------------------------------------------------------------
__global__ __launch_bounds__(256) void k_gemm_node(
    const u16* __restrict__ H, const float* __restrict__ R,
    const u16* __restrict__ WT, const float* __restrict__ recvf,
    u16* __restrict__ O16, float* __restrict__ O32, int fin, int M)
{
    __shared__ u16 As[128][72];
    __shared__ u16 Bs[128][72];
    const int t = threadIdx.x;
    const int m0 = blockIdx.x * 128;
    const int w = t >> 6, lane = t & 63, wm = w >> 1, wn = w & 1;
    f32x4 acc[4][4] = {};

    const int row = t >> 1, koff = (t & 1) * 32;
    const int gm_s = m0 + row;

    for (int kt = 0; kt < 256; kt += 64) {
        if (kt < 128) {
            #pragma unroll
            for (int j = 0; j < 4; ++j) {
                int4 va = make_int4(0, 0, 0, 0);
                if (gm_s < M) va = *(const int4*)(H + (size_t)gm_s * 128 + kt + koff + j * 8);
                *(int4*)&As[row][koff + j * 8] = va;
            }
        } else {
            #pragma unroll
            for (int j = 0; j < 8; ++j) {
                float4 v = make_float4(0.f, 0.f, 0.f, 0.f);
                if (gm_s < M) v = *(const float4*)(R + (size_t)gm_s * 128 + (kt - 128) + koff + j * 4);
                ushort4 o;
                o.x = f2b(v.x); o.y = f2b(v.y); o.z = f2b(v.z); o.w = f2b(v.w);
                *(ushort4*)&As[row][koff + j * 4] = o;
            }
        }
        #pragma unroll
        for (int j = 0; j < 4; ++j)
            *(int4*)&Bs[row][koff + j * 8] =
                *(const int4*)(WT + (size_t)row * 256 + kt + koff + j * 8);
        __syncthreads();
        #pragma unroll
        for (int kf = 0; kf < 2; ++kf) {
            s16x8 a[4], b[4];
            #pragma unroll
            for (int mi = 0; mi < 4; ++mi)
                a[mi] = *(const s16x8*)&As[wm * 64 + mi * 16 + (lane & 15)][kf * 32 + (lane >> 4) * 8];
            #pragma unroll
            for (int ni = 0; ni < 4; ++ni)
                b[ni] = *(const s16x8*)&Bs[wn * 64 + ni * 16 + (lane & 15)][kf * 32 + (lane >> 4) * 8];
            #pragma unroll
            for (int mi = 0; mi < 4; ++mi)
                #pragma unroll
                for (int ni = 0; ni < 4; ++ni)
                    acc[mi][ni] = __builtin_amdgcn_mfma_f32_16x16x32_bf16(
                        a[mi], b[ni], acc[mi][ni], 0, 0, 0);
        }
        __syncthreads();
    }
    const int lr = (lane >> 4) * 4, lc = lane & 15;
    #pragma unroll
    for (int mi = 0; mi < 4; ++mi) {
        #pragma unroll
        for (int r = 0; r < 4; ++r) {
            int gm = m0 + wm * 64 + mi * 16 + lr + r;
            if (gm < M) {
                float rv = recvf[gm];
                #pragma unroll
                for (int ni = 0; ni < 4; ++ni) {
                    float val = leaky(acc[mi][ni][r]) * rv;
                    size_t o = (size_t)gm * 128 + wn * 64 + ni * 16 + lc;
                    if (fin) O32[o] = val;
                    else     O16[o] = f2b(val);
                }
            }
        }
    }
}

// ---------------------------------------------------------------------------
// Edge pass over DST-SORTED active edges: MFMA matvec + LDS transpose +
// run-merged coalesced atomics (one atomic pair per same-dst run per wave).
// ---------------------------------------------------------------------------
__global__ __launch_bounds__(256) void k_edge(
    const float* __restrict__ ef, const u16* __restrict__ WTef,  // [128 n][64 k] bf16
    const u16* __restrict__ T16, const int* __restrict__ eS,
    const int* __restrict__ sSg, const int* __restrict__ dSg,
    const int* __restrict__ cntp, float* __restrict__ red)
{
    __shared__ u16 Et[64][72];           // ef tile, edge-major bf16
    __shared__ u16 Ms[64][136];          // msg bf16, edge-major, padded
    __shared__ int sS[EPB], sD[EPB];

    const int t = threadIdx.x;
    const int cnt = *cntp;
    const int b0 = blockIdx.x * EPB;
    if (b0 >= cnt) return;

    if (t < EPB) {
        int p = b0 + t;
        sS[t] = (p < cnt) ? sSg[p] : -1;
        sD[t] = (p < cnt) ? dSg[p] : -1;
    }

    #pragma unroll
    for (int pz = 0; pz < 4; ++pz) {     // stage ef: 64 edges x 16 float4
        int idx = t + pz * 256;
        int edge = idx >> 4, f4 = idx & 15;
        int p = b0 + edge;
        float4 v = make_float4(0.f, 0.f, 0.f, 0.f);
        if (p < cnt) v = *(const float4*)(ef + (size_t)eS[p] * 64 + f4 * 4);
        ushort4 o;
        o.x = f2b(v.x); o.y = f2b(v.y); o.z = f2b(v.z); o.w = f2b(v.w);
        *(ushort4*)&Et[edge][f4 * 4] = o;
    }
    __syncthreads();

    const int w = t >> 6, lane = t & 63;
    const int lo = lane & 15, q = lane >> 4;
    const int ei = w * 16 + lo;          // this lane's edge slot

    f32x4 acc[8] = {};
    #pragma unroll
    for (int kf = 0; kf < 2; ++kf) {
        s16x8 b = *(const s16x8*)&Et[ei][kf * 32 + q * 8];
        #pragma unroll
        for (int mi = 0; mi < 8; ++mi) {
            s16x8 a = *(const s16x8*)(WTef + (size_t)(mi * 16 + lo) * 64 + kf * 32 + q * 8);
            acc[mi] = __builtin_amdgcn_mfma_f32_16x16x32_bf16(a, b, acc[mi], 0, 0, 0);
        }
    }
    // D mapping: col=lane&15 (edge), row = mi*16 + q*4 + r (feature n)
    #pragma unroll
    for (int mi = 0; mi < 8; ++mi) {
        ushort4 o;
        o.x = f2b(acc[mi][0]); o.y = f2b(acc[mi][1]);
        o.z = f2b(acc[mi][2]); o.w = f2b(acc[mi][3]);
        *(ushort4*)&Ms[ei][mi * 16 + q * 4] = o;
    }
    __syncthreads();

    // scatter: wave w walks edges w*16..w*16+15 (dst-sorted); accumulate per
    // same-dst run; one coalesced atomic pair per run.
    float a0 = 0.f, a1 = 0.f;
    int dprev = -1;
    float td0 = 0.f, td1 = 0.f;
    for (int ii = 0; ii < 16; ++ii) {
        int e2 = w * 16 + ii;
        if (b0 + e2 >= cnt) break;       // any pending run was flushed below
        int d = sD[e2], s = sS[e2];
        if (d != dprev) {
            td0 = b2f(T16[(size_t)d * 256 + 128 + lane]);
            td1 = b2f(T16[(size_t)d * 256 + 192 + lane]);
            dprev = d;
        }
        float t0 = b2f(T16[(size_t)s * 256 + lane]);
        float t1 = b2f(T16[(size_t)s * 256 + 64 + lane]);
        a0 += leaky(b2f(Ms[e2][lane])      + t0 + td0);
        a1 += leaky(b2f(Ms[e2][64 + lane]) + t1 + td1);
        bool last = (ii == 15) || (b0 + e2 + 1 >= cnt) || (sD[e2 + 1] != d);
        if (last) {
            atomicAdd(red + (size_t)d * 128 + lane,      a0);
            atomicAdd(red + (size_t)d * 128 + 64 + lane, a1);
            a0 = 0.f; a1 = 0.f;
        }
    }
}

// ---------------------------------------------------------------------------
extern "C" void kernel_launch(void* const* d_in, const int* in_sizes, int n_in,
                              void* d_out, int out_size, void* d_ws, size_t ws_size,
                              hipStream_t stream)
{
    const float* nf    = (const float*)d_in[0];
    const float* ef    = (const float*)d_in[1];
    const int*   src   = (const int*)d_in[2];
    const int*   dst   = (const int*)d_in[3];
    const int*   ntype = (const int*)d_in[4];
    const float* We[3] = {(const float*)d_in[5], (const float*)d_in[7], (const float*)d_in[9]};
    const float* Wn[3] = {(const float*)d_in[6], (const float*)d_in[8], (const float*)d_in[10]};

    const int N = in_sizes[0] / 128;
    const int E = in_sizes[1] / 64;

    u16* T16  = (u16*)d_ws;                        // N*256
    u16* hb0  = T16 + (size_t)N * 256;             // N*128
    u16* hb1  = hb0 + (size_t)N * 128;             // N*128
    u16* WTe  = hb1 + (size_t)N * 128;             // 3*2*16384
    u16* WTn  = WTe + 3 * 2 * 16384;               // 3*32768
    u16* WTef = WTn + 3 * 32768;                   // 3*8192
    float* red   = (float*)(WTef + 3 * 8192);      // N*128 fp32
    float* recvf = red + (size_t)N * 128;          // N
    int* deg    = (int*)(recvf + N);               // N
    int* cursor = deg + N;                         // N
    int* bsum   = cursor + N;                      // 256
    int* cntp   = bsum + 256;                      // 1 (+pad)
    int* eS     = cntp + 4;                        // E
    int* sSg    = eS + E;                          // E
    int* dSg    = sSg + E;                         // E

    const int nb = (N + 255) / 256;                // <= 256 required (N=50000 -> 196)

    hipMemsetAsync(deg, 0, (size_t)N * sizeof(int), stream);
    hipMemsetAsync(recvf, 0, (size_t)N * sizeof(float), stream);
    k_hist<<<(E + 255) / 256, 256, 0, stream>>>(src, dst, ntype, deg, recvf, E);
    k_scan1<<<nb, 256, 0, stream>>>(deg, bsum, N);
    k_scan2<<<1, 256, 0, stream>>>(bsum, nb, cntp);
    k_scan3<<<nb, 256, 0, stream>>>(deg, bsum, cursor, N);
    k_scatter_pos<<<(E + 255) / 256, 256, 0, stream>>>(src, dst, ntype, cursor, eS, sSg, dSg, E);

    // nf -> bf16
    k_f2b<<<(N * 128 / 4 + 255) / 256, 256, 0, stream>>>(nf, hb0, N * 128 / 4);

    // per-layer weight transposes (bf16)
    for (int l = 0; l < 3; ++l) {
        k_wt<<<(128 * 128 + 255) / 256, 256, 0, stream>>>(We[l],             WTe + (size_t)l * 2 * 16384,         128);
        k_wt<<<(128 * 128 + 255) / 256, 256, 0, stream>>>(We[l] + 128 * 128, WTe + (size_t)l * 2 * 16384 + 16384, 128);
        k_wt<<<(256 * 128 + 255) / 256, 256, 0, stream>>>(Wn[l],             WTn + (size_t)l * 32768,             256);
        k_wt<<<(64 * 128 + 255) / 256, 256, 0, stream>>>(We[l] + 256 * 128,  WTef + (size_t)l * 8192,             64);
    }

    dim3 gT((N + 127) / 128, 2);
    dim3 gN((N + 127) / 128, 1);
    int  gE = (E + EPB - 1) / EPB;

    const u16* hIn[3]  = {hb0, hb1, hb0};
    u16*       hOut[3] = {hb1, hb0, hb1};
    for (int l = 0; l < 3; ++l) {
        int fin = (l == 2);
        k_gemm_T<<<gT, 256, 0, stream>>>(hIn[l], WTe + (size_t)l * 2 * 16384, T16, N);
        hipMemsetAsync(red, 0, (size_t)N * 128 * sizeof(float), stream);
        k_edge<<<gE, 256, 0, stream>>>(ef, WTef + (size_t)l * 8192, T16, eS, sSg, dSg, cntp, red);
        k_gemm_node<<<gN, 256, 0, stream>>>(hIn[l], red, WTn + (size_t)l * 32768,
                                            recvf, hOut[l], (float*)d_out, fin, N);
    }
}